// Round 5
// baseline (1632.713 us; speedup 1.0000x reference)
//
#include <hip/hip_runtime.h>

typedef unsigned short u16;
typedef __attribute__((ext_vector_type(8))) short short8;
typedef __attribute__((ext_vector_type(4))) short short4v;
typedef __attribute__((ext_vector_type(4))) float floatx4;

#define CDIM 1024
#define NB 4

__device__ __forceinline__ float bf2f(u16 u) {
  union { unsigned int i; float f; } v; v.i = ((unsigned int)u) << 16; return v.f;
}
__device__ __forceinline__ u16 f2bf(float f) {
  union { float f; unsigned int i; } v; v.f = f;
  unsigned int r = v.i + 0x7fffu + ((v.i >> 16) & 1u);
  return (u16)(r >> 16);
}
__device__ __forceinline__ float san(float f) {
  return (fabsf(f) <= 3.0e38f) ? f : 0.f;
}
// dtype-flagged input load: flag 1 = fp32, 0 = bf16
__device__ __forceinline__ float ldin(const void* p, size_t i, int f) {
  return f ? san(((const float*)p)[i]) : bf2f(((const u16*)p)[i]);
}

constexpr int cipow(int b, int e) { return e ? b * cipow(b, e - 1) : 1; }

// LDS position swizzle: short-index of (pos, row r) is swz(pos)+r.
// XOR of pos-bits 3..5 into the bank bits spreads loadV's b16 writes
// from 16-way to ~4-way conflicts; pure permutation within each
// 8-position block, b64 alignment preserved.
__device__ __forceinline__ int swz(int pos) {
  return (pos << 2) ^ ((pos >> 1) & 28);
}

// async global->LDS, 16B per lane. LDS dest must be wave-uniform base + lane*16.
__device__ __forceinline__ void gload16(const u16* g, u16* l) {
  __builtin_amdgcn_global_load_lds(
      (const __attribute__((address_space(1))) void*)g,
      (__attribute__((address_space(3))) void*)l, 16, 0, 0);
}

// ---------------- per-tensor dtype sniffer ----------------
struct PtrArgs { const void* p[22]; int n[22]; };

__global__ void detect_dtypes(PtrArgs a, int* __restrict__ flags) {
  __shared__ int cnt;
  int ti = blockIdx.x;
  if (threadIdx.x == 0) cnt = 0;
  __syncthreads();
  if (ti >= 22) {
    if (threadIdx.x == 0) flags[ti] = 0;
    return;
  }
  const u16* u = (const u16*)a.p[ti];
  int m = a.n[ti]; if (m > 4096) m = 4096;
  int local = 0;
  for (int i = threadIdx.x; i < m; i += blockDim.x) {
    int e = (u[i] >> 7) & 0xFF;
    if (e != 0 && (e < 97 || e > 158)) local++;
  }
  atomicAdd(&cnt, local);
  __syncthreads();
  if (threadIdx.x == 0) flags[ti] = (cnt >= (m >> 6) + 2) ? 1 : 0;
}

// ---------------- weight pre-conversion: flagged (fp32|bf16) -> bf16 arena ----
struct W5 { const void* p[5]; int fi[5]; };

__global__ void conv_w(W5 w, u16* __restrict__ out, const int* __restrict__ flags) {
  int wi = blockIdx.y;
  int f = flags[w.fi[wi]];
  size_t base = (size_t)wi * (CDIM * CDIM);
  int t = blockIdx.x * blockDim.x + threadIdx.x;   // 0 .. CDIM*CDIM/8-1
  size_t e = (size_t)t * 8;
  if (f) {
    const float4* in = (const float4*)w.p[wi];
    float4 a0 = in[t * 2], a1 = in[t * 2 + 1];
    __align__(16) u16 tmp[8];
    tmp[0] = f2bf(san(a0.x)); tmp[1] = f2bf(san(a0.y));
    tmp[2] = f2bf(san(a0.z)); tmp[3] = f2bf(san(a0.w));
    tmp[4] = f2bf(san(a1.x)); tmp[5] = f2bf(san(a1.y));
    tmp[6] = f2bf(san(a1.z)); tmp[7] = f2bf(san(a1.w));
    *(uint4*)&out[base + e] = *(uint4*)tmp;
  } else {
    const uint4* in = (const uint4*)w.p[wi];
    *(uint4*)&out[base + e] = in[t];
  }
}

// ---------------- transpose + zero-pad (dtype-flagged input -> bf16) ----
__global__ void transpose_pad(const void* __restrict__ inv, u16* __restrict__ out,
                              int Lin, int Lout, const int* __restrict__ flags, int fidx) {
  __shared__ u16 t[32][33];
  int f = flags[fidx];
  int b = blockIdx.z;
  int l0 = blockIdx.x * 32, c0 = blockIdx.y * 32;
  int x = threadIdx.x, y = threadIdx.y;
  bool valid = (l0 < Lin);   // Lin % 32 == 0: whole tile valid or whole tile pad
  if (valid) {
    for (int r = 0; r < 4; r++) {
      size_t idx = ((size_t)b * CDIM + c0 + y * 4 + r) * Lin + l0 + x;
      t[y * 4 + r][x] = f2bf(ldin(inv, idx, f));
    }
  }
  __syncthreads();
  for (int r = 0; r < 4; r++) {
    int lr = l0 + y * 4 + r;
    out[((size_t)b * Lout + lr) * CDIM + c0 + x] = valid ? t[x][y * 4 + r] : (u16)0;
  }
}

// ---------------- bf16 MFMA GEMM with BN epilogue (m97 structure) ----------
#define BK 32

__global__ __launch_bounds__(256) void gemm_bn(
    const u16* __restrict__ Wb, const u16* __restrict__ XT, void* __restrict__ Out,
    const void* __restrict__ sc, const void* __restrict__ sh, int Lpad,
    const int* __restrict__ flags, int sci, int shi, int f32out) {
  __shared__ __align__(16) u16 As[128 * BK];
  __shared__ __align__(16) u16 Bs[128 * BK];
  const int K = 1024;
  int tid = threadIdx.x;
  int lane = tid & 63, wave = tid >> 6;
  int m0 = blockIdx.y * 128, n0 = blockIdx.x * 128;
  int wm = (wave >> 1) * 64, wn = (wave & 1) * 64;
  int srow = lane >> 2;
  int scol = (lane & 3) * 8;
  const u16* Ag = Wb + (size_t)(m0 + wave * 32 + srow) * K + scol;
  const u16* Bg = XT + (size_t)(n0 + wave * 32 + srow) * K + scol;
  u16* Asl = &As[(wave * 32 + srow) * BK + scol];
  u16* Bsl = &Bs[(wave * 32 + srow) * BK + scol];
  floatx4 acc[4][4] = {};
  for (int k0 = 0; k0 < K; k0 += BK) {
    __syncthreads();
#pragma unroll
    for (int i = 0; i < 2; i++) {
      gload16(Ag + (size_t)(i * 16) * K + k0, Asl + i * 16 * BK);
      gload16(Bg + (size_t)(i * 16) * K + k0, Bsl + i * 16 * BK);
    }
    __syncthreads();
    int lr = lane & 15, q8 = (lane >> 4) * 8;
    short8 af[4], bfr[4];
#pragma unroll
    for (int f = 0; f < 4; f++) {
      af[f]  = *(const short8*)&As[(wm + f * 16 + lr) * BK + q8];
      bfr[f] = *(const short8*)&Bs[(wn + f * 16 + lr) * BK + q8];
    }
#pragma unroll
    for (int i = 0; i < 4; i++)
#pragma unroll
      for (int j = 0; j < 4; j++)
        acc[i][j] = __builtin_amdgcn_mfma_f32_16x16x32_bf16(af[i], bfr[j], acc[i][j], 0, 0, 0);
  }
  int sf = flags[sci], hf = flags[shi];
  int colL = lane & 15, rq = (lane >> 4) * 4;
  int b = n0 / Lpad;
  int lb = n0 - b * Lpad;
#pragma unroll
  for (int i = 0; i < 4; i++) {
    int gr0 = m0 + wm + i * 16 + rq;
    float s0 = ldin(sc, gr0, sf),     h0 = ldin(sh, gr0, hf);
    float s1 = ldin(sc, gr0 + 1, sf), h1 = ldin(sh, gr0 + 1, hf);
    float s2 = ldin(sc, gr0 + 2, sf), h2 = ldin(sh, gr0 + 2, hf);
    float s3 = ldin(sc, gr0 + 3, sf), h3 = ldin(sh, gr0 + 3, hf);
#pragma unroll
    for (int j = 0; j < 4; j++) {
      int gc = lb + wn + j * 16 + colL;
      size_t base = ((size_t)b * CDIM + gr0) * Lpad + gc;
      float r0 = acc[i][j][0] * s0 + h0;
      float r1 = acc[i][j][1] * s1 + h1;
      float r2 = acc[i][j][2] * s2 + h2;
      float r3 = acc[i][j][3] * s3 + h3;
      if (f32out) {
        float* O = (float*)Out;
        O[base]                    = r0;
        O[base + (size_t)Lpad]     = r1;
        O[base + 2 * (size_t)Lpad] = r2;
        O[base + 3 * (size_t)Lpad] = r3;
      } else {
        u16* O = (u16*)Out;
        O[base]                    = f2bf(r0);
        O[base + (size_t)Lpad]     = f2bf(r1);
        O[base + 2 * (size_t)Lpad] = f2bf(r2);
        O[base + 3 * (size_t)Lpad] = f2bf(r3);
      }
    }
  }
}

// ---------------- attention P precompute ----------------
// P slot stride padded to 16B multiple: base2 -> 4 floats, base3 -> 12 floats.
template<int BASE>
__global__ void p_compute(const u16* __restrict__ qk, float* __restrict__ P,
                          int Lstride, int n, int G) {
  constexpr int PSTR = (BASE == 2) ? 4 : 12;
  int lev = blockIdx.y;
  int t = blockIdx.x * blockDim.x + threadIdx.x;
  if (t >= 32 * G) return;
  int g = t % G, bh = t / G;
  int inner = 1;
  for (int i = 0; i < n - 1 - lev; i++) inner *= BASE;
  int ii = g / inner, kk = g - ii * inner;
  const u16* qp = qk + ((size_t)bh * 128) * Lstride;
  const u16* kp = qk + ((size_t)bh * 128 + 64) * Lstride;
  int lpos[BASE];
#pragma unroll
  for (int j = 0; j < BASE; j++) lpos[j] = (ii * BASE + j) * inner + kk;
  float S[BASE][BASE];
#pragma unroll
  for (int J = 0; J < BASE; J++)
#pragma unroll
    for (int j = 0; j < BASE; j++) S[J][j] = 0.f;
  for (int d = 0; d < 64; d++) {
    float qv[BASE], kv[BASE];
#pragma unroll
    for (int j = 0; j < BASE; j++) {
      qv[j] = bf2f(qp[(size_t)d * Lstride + lpos[j]]);
      kv[j] = bf2f(kp[(size_t)d * Lstride + lpos[j]]);
    }
#pragma unroll
    for (int J = 0; J < BASE; J++)
#pragma unroll
      for (int j = 0; j < BASE; j++) S[J][j] += kv[J] * qv[j];
  }
  float* Pg = P + ((size_t)lev * 32 * G + t) * PSTR;
#pragma unroll
  for (int J = 0; J < BASE; J++) {
    float mx = -1e30f;
#pragma unroll
    for (int j = 0; j < BASE; j++) { S[J][j] *= 0.125f; mx = fmaxf(mx, S[J][j]); }
    float e[BASE]; float sum = 0.f;
#pragma unroll
    for (int j = 0; j < BASE; j++) { e[j] = __expf(S[J][j] - mx); sum += e[j]; }
    float inv = 1.f / sum;
#pragma unroll
    for (int j = 0; j < BASE; j++) Pg[J * BASE + j] = e[j] * inv;
  }
}

// ---------------- in-LDS level apply, 4 rows per block ----------------
// LDS layout: Wl[swz(pos) + r] bf16 (r = row within the 4-row batch).
// One P load per group feeds 4 rows (b64 LDS ops). Groups thread-disjoint.
template<int B, int N, int p>
__device__ __forceinline__ void lds_group(u16* __restrict__ Wl,
                                          const float* __restrict__ Pl, int g) {
  constexpr int inner = cipow(B, p);
  constexpr int PSTR = (B == 2) ? 4 : 12;
  int ii = g / inner, kk = g - ii * inner;
  int base = ii * (B * inner) + kk;
  const float4* Pg = (const float4*)(Pl + (size_t)g * PSTR);
  if constexpr (B == 2) {
    float4 pv = Pg[0];
    short4v a = *(short4v*)&Wl[swz(base)];
    short4v b = *(short4v*)&Wl[swz(base + inner)];
#pragma unroll
    for (int r = 0; r < 4; r++) {
      float i0 = bf2f((u16)a[r]), i1 = bf2f((u16)b[r]);
      a[r] = (short)f2bf(pv.x * i0 + pv.y * i1);
      b[r] = (short)f2bf(pv.z * i0 + pv.w * i1);
    }
    *(short4v*)&Wl[swz(base)] = a;
    *(short4v*)&Wl[swz(base + inner)] = b;
  } else {
    float4 A = Pg[0], Bv = Pg[1], Cv = Pg[2];
    short4v a = *(short4v*)&Wl[swz(base)];
    short4v b = *(short4v*)&Wl[swz(base + inner)];
    short4v c = *(short4v*)&Wl[swz(base + 2 * inner)];
#pragma unroll
    for (int r = 0; r < 4; r++) {
      float i0 = bf2f((u16)a[r]), i1 = bf2f((u16)b[r]), i2 = bf2f((u16)c[r]);
      a[r] = (short)f2bf(A.x  * i0 + A.y  * i1 + A.z  * i2);
      b[r] = (short)f2bf(A.w  * i0 + Bv.x * i1 + Bv.y * i2);
      c[r] = (short)f2bf(Bv.z * i0 + Bv.w * i1 + Cv.x * i2);
    }
    *(short4v*)&Wl[swz(base)] = a;
    *(short4v*)&Wl[swz(base + inner)] = b;
    *(short4v*)&Wl[swz(base + 2 * inner)] = c;
  }
}

template<int B, int N, int p>
__device__ __forceinline__ void lds_level4(u16* __restrict__ Wl,
                                           const float* __restrict__ Pl) {
  constexpr int G = cipow(B, N) / B;
#pragma unroll
  for (int it = 0; it < G / 256; it++)
    lds_group<B, N, p>(Wl, Pl, it * 256 + (int)threadIdx.x);
  if constexpr ((G % 256) != 0) {
    int g = (G / 256) * 256 + (int)threadIdx.x;
    if (g < G) lds_group<B, N, p>(Wl, Pl, g);
  }
}

template<int B, int N, int p, bool up>
__device__ __forceinline__ void chain_rec4(u16* __restrict__ Wl,
                                           const float* __restrict__ Pb, int bh) {
  constexpr int G = cipow(B, N) / B;
  constexpr int PSTR = (B == 2) ? 4 : 12;
  constexpr size_t PLEV = (size_t)32 * G * PSTR;
  __syncthreads();
  lds_level4<B, N, p>(Wl, Pb + (size_t)(N - 1 - p) * PLEV + (size_t)bh * G * PSTR);
  if constexpr (up) {
    if constexpr (p + 1 < N) chain_rec4<B, N, p + 1, true>(Wl, Pb, bh);
  } else {
    if constexpr (p > 0) chain_rec4<B, N, p - 1, false>(Wl, Pb, bh);
  }
}

// ---------------- fused attention chains + combine (4 rows/block) --------
// Block handles rows row0..row0+3 (same bh). LDS holds the 4 rows bf16 in
// swizzled [pos][row] layout. Chain v1 -> stash first 4096 positions to
// global scratch v1s (bf16, bit-identical to the LDS values). Reload v0,
// chain v2, then one-pass epilogue:
//   y = x + v1s + Wl(v2) + BN(dwconv3(v0 re-read from global, L2-hot)).
// No long-lived register accumulator -> no scratch spill.
// xres may alias y (stage 3): thread reads its elems before writing them.
template<int BASE, int N, int LSTR>
__global__ __launch_bounds__(256, 2) void fused_chains(
    const u16* __restrict__ v0, const void* __restrict__ xres,
    const void* __restrict__ wpe, const void* __restrict__ spe,
    const void* __restrict__ bpe, u16* __restrict__ y,
    u16* __restrict__ v1s,
    const float* __restrict__ Pb, const int* __restrict__ flags,
    int xfi, int wpi, int spi, int bpi) {
  constexpr int L = cipow(BASE, N);
  constexpr int LW = (L + 7) & ~7;          // positions loaded (mult of 8)
  __shared__ __align__(16) u16 Wl[LW * 4];
  // XCD swizzle: 1024 blocks % 8 == 0 -> bijective; blocks of one bh (32)
  // land on one XCD so the shared P set stays in a single L2.
  int cpx = (int)gridDim.x >> 3;
  int blk = ((int)blockIdx.x & 7) * cpx + ((int)blockIdx.x >> 3);
  int row0 = blk * 4;
  int bh = row0 >> 7;
  int tid = threadIdx.x;

  auto loadV = [&]() {
#pragma unroll 2
    for (int i = tid; i < (LW / 8) * 4; i += 256) {
      int r = i & 3, ch = i >> 2;
      short8 x = *(const short8*)&v0[(size_t)(row0 + r) * LSTR + ch * 8];
#pragma unroll
      for (int k = 0; k < 8; k++) Wl[swz(ch * 8 + k) + r] = (u16)x[k];
    }
  };

  int l0 = tid * 16;                        // output positions l0..l0+15

  // ---- chain v1: digits ascending p = 0..N-1 (original i = N-1..0) ----
  loadV();
  chain_rec4<BASE, N, 0, true>(Wl, Pb, bh);  // leading barrier covers loadV
  __syncthreads();
  // stash chain-1 result (only the first 4096 positions feed the output)
#pragma unroll
  for (int r = 0; r < 4; r++) {
    short8 o0, o1;
#pragma unroll
    for (int k = 0; k < 8; k++) {
      o0[k] = (short)Wl[swz(l0 + k) + r];
      o1[k] = (short)Wl[swz(l0 + 8 + k) + r];
    }
    size_t vb = (size_t)(row0 + r) * 4096 + l0;
    *(short8*)&v1s[vb] = o0;
    *(short8*)&v1s[vb + 8] = o1;
  }
  __syncthreads();                          // stash reads done before reload
  // ---- chain v2: digits descending p = N-1..0 (original i = 0..N-1) ----
  loadV();
  chain_rec4<BASE, N, N - 1, false>(Wl, Pb, bh);  // leading barrier covers loadV
  __syncthreads();

  // ---- one-pass epilogue ----
  int c0 = row0 & (CDIM - 1);
  int xf = flags[xfi], wf = flags[wpi], sf = flags[spi], bfg = flags[bpi];
#pragma unroll
  for (int r = 0; r < 4; r++) {
    int cr = c0 + r;
    const u16* vr = v0 + (size_t)(row0 + r) * LSTR;
    float w0 = ldin(wpe, (size_t)cr * 3, wf);
    float w1 = ldin(wpe, (size_t)cr * 3 + 1, wf);
    float w2 = ldin(wpe, (size_t)cr * 3 + 2, wf);
    float scv = ldin(spe, cr, sf), bcv = ldin(bpe, cr, bfg);
    // v0 window (global, L2/L3-hot after two loadV passes)
    short8 vc0 = *(const short8*)&vr[l0];
    short8 vc1 = *(const short8*)&vr[l0 + 8];
    float vcf[16];
#pragma unroll
    for (int k = 0; k < 8; k++) {
      vcf[k] = bf2f((u16)vc0[k]);
      vcf[k + 8] = bf2f((u16)vc1[k]);
    }
    float vml = (l0 > 0) ? bf2f(vr[l0 - 1]) : 0.f;
    float vpr = (l0 + 16 < L) ? bf2f(vr[l0 + 16]) : 0.f;
    size_t xb = (size_t)(row0 + r) * 4096 + l0;
    float xr[16];
    if (xf) {
      const float* X = (const float*)xres;
#pragma unroll
      for (int k = 0; k < 16; k += 4) {
        float4 x4 = *(const float4*)&X[xb + k];
        xr[k] = san(x4.x); xr[k + 1] = san(x4.y);
        xr[k + 2] = san(x4.z); xr[k + 3] = san(x4.w);
      }
    } else {
      const u16* X = (const u16*)xres;
#pragma unroll
      for (int k8 = 0; k8 < 2; k8++) {
        short8 x8 = *(const short8*)&X[xb + k8 * 8];
#pragma unroll
        for (int k = 0; k < 8; k++) xr[k8 * 8 + k] = bf2f((u16)x8[k]);
      }
    }
    short8 s10 = *(const short8*)&v1s[xb];
    short8 s11 = *(const short8*)&v1s[xb + 8];
    short8 o0, o1;
#pragma unroll
    for (int k = 0; k < 16; k++) {
      float vm = k ? vcf[k - 1] : vml;
      float vp = (k < 15) ? vcf[k + 1] : vpr;
      float pe = (w0 * vm + w1 * vcf[k] + w2 * vp) * scv + bcv;
      float v1v = bf2f((u16)((k < 8) ? s10[k] : s11[k - 8]));
      float v2v = bf2f(Wl[swz(l0 + k) + r]);
      float res = xr[k] + v1v + v2v + pe;
      if (k < 8) o0[k] = (short)f2bf(res); else o1[k - 8] = (short)f2bf(res);
    }
    *(short8*)&y[xb] = o0;
    *(short8*)&y[xb + 8] = o1;
  }
}

extern "C" void kernel_launch(void* const* d_in, const int* in_sizes, int n_in,
                              void* d_out, int out_size, void* d_ws, size_t ws_size,
                              hipStream_t stream) {
  const int W = 4096;
  const int Ls2 = 4096;                 // stage2 stride == L2
  const int Ls3 = 6656;                 // stage3: stride (52*128), L3 = 6561
  const int G2 = 2048, G3 = 2187;       // groups per (b,H)
  const size_t S3e = (size_t)NB * CDIM * Ls3;   // 27,262,976 elements

  // Arena: 3 bf16 slots + flags + bf16 weight arena ≈ 174 MB.
  // Pbuf aliases slotA: xT is dead once both GEMMs have run (sequential
  // stream), and P is dead before the next transpose writes slotA again.
  // slotB doubles as the chain-1 stash inside fused_chains (qk is dead
  // once p_compute has run).
  char* p = (char*)d_ws;
  auto alloc = [&](size_t bytes) { char* r = p; p += (bytes + 255) & ~(size_t)255; return r; };
  u16* slotA = (u16*)alloc(S3e * 2);   // xT ; later aliased by Pbuf
  u16* slotB = (u16*)alloc(S3e * 2);   // qk ; later chain-1 stash
  u16* slotC = (u16*)alloc(S3e * 2);   // v0
  int* flags = (int*)alloc(64 * 4);
  u16* warena = (u16*)alloc((size_t)5 * CDIM * CDIM * 2);  // 5 bf16 weight copies
  float* Pbuf = (float*)slotA;         // max P: base3 = 8*32*2187*12*4 B = 33.6 MB
  (void)ws_size; (void)n_in; (void)out_size;

  // y2/y3 staging (bf16) lives in the front half of d_out.
  u16* ybuf = (u16*)d_out;

  // ---- dtype sniff (writes flags[0..21]; flags[22]=0 = bf16 sentinel) ----
  PtrArgs pa;
  for (int i = 0; i < 22; i++) { pa.p[i] = d_in[i]; pa.n[i] = in_sizes[i]; }
  detect_dtypes<<<23, 256, 0, stream>>>(pa, flags);
  const int BF = 22;  // sentinel flag index (bf16)

  // ---- pre-convert the 5 GEMM weights to bf16 arena (flag-driven) ----
  W5 w5;
  const int widx[5] = {1, 4, 10, 13, 19};
  for (int i = 0; i < 5; i++) { w5.p[i] = d_in[widx[i]]; w5.fi[i] = widx[i]; }
  conv_w<<<dim3(CDIM * CDIM / 8 / 256, 5), 256, 0, stream>>>(w5, warena, flags);
  u16* wb_qk2 = warena;
  u16* wb_v2  = warena + (size_t)1 * CDIM * CDIM;
  u16* wb_qk3 = warena + (size_t)2 * CDIM * CDIM;
  u16* wb_v3  = warena + (size_t)3 * CDIM * CDIM;
  u16* wb_pr  = warena + (size_t)4 * CDIM * CDIM;

  dim3 tb(32, 8);

  // ================= stage base=2 (n=12, L=4096, no pad) =================
  transpose_pad<<<dim3(Ls2 / 32, CDIM / 32, NB), tb, 0, stream>>>(d_in[0], slotA, W, Ls2, flags, 0);
  gemm_bn<<<dim3(NB * Ls2 / 128, CDIM / 128), 256, 0, stream>>>(
      wb_qk2, slotA, slotB, d_in[2], d_in[3], Ls2, flags, 2, 3, 0);
  gemm_bn<<<dim3(NB * Ls2 / 128, CDIM / 128), 256, 0, stream>>>(
      wb_v2, slotA, slotC, d_in[5], d_in[6], Ls2, flags, 5, 6, 0);
  p_compute<2><<<dim3((32 * G2 + 255) / 256, 12), 256, 0, stream>>>(slotB, Pbuf, Ls2, 12, G2);
  fused_chains<2, 12, 4096><<<NB * CDIM / 4, 256, 0, stream>>>(
      slotC, d_in[0], d_in[7], d_in[8], d_in[9], ybuf, slotB, Pbuf, flags, 0, 7, 8, 9);

  // ================= stage base=3 (n=8, L=6561, stride 6656) =================
  transpose_pad<<<dim3(Ls3 / 32, CDIM / 32, NB), tb, 0, stream>>>(ybuf, slotA, W, Ls3, flags, BF);
  gemm_bn<<<dim3(NB * Ls3 / 128, CDIM / 128), 256, 0, stream>>>(
      wb_qk3, slotA, slotB, d_in[11], d_in[12], Ls3, flags, 11, 12, 0);
  gemm_bn<<<dim3(NB * Ls3 / 128, CDIM / 128), 256, 0, stream>>>(
      wb_v3, slotA, slotC, d_in[14], d_in[15], Ls3, flags, 14, 15, 0);
  p_compute<3><<<dim3((32 * G3 + 255) / 256, 8), 256, 0, stream>>>(slotB, Pbuf, Ls3, 8, G3);
  fused_chains<3, 8, 6656><<<NB * CDIM / 4, 256, 0, stream>>>(
      slotC, ybuf, d_in[16], d_in[17], d_in[18], ybuf, slotB, Pbuf, flags, BF, 16, 17, 18);

  // ================= final projection (fp32 output!) =================
  transpose_pad<<<dim3(Ls2 / 32, CDIM / 32, NB), tb, 0, stream>>>(ybuf, slotA, W, Ls2, flags, BF);
  gemm_bn<<<dim3(NB * Ls2 / 128, CDIM / 128), 256, 0, stream>>>(
      wb_pr, slotA, d_out, d_in[20], d_in[21], Ls2, flags, 20, 21, 1);
}

// Round 6
// 1005.671 us; speedup vs baseline: 1.6235x; 1.6235x over previous
//
#include <hip/hip_runtime.h>

typedef unsigned short u16;
typedef __attribute__((ext_vector_type(8))) short short8;
typedef __attribute__((ext_vector_type(4))) float floatx4;

#define CDIM 1024
#define NB 4

__device__ __forceinline__ float bf2f(u16 u) {
  union { unsigned int i; float f; } v; v.i = ((unsigned int)u) << 16; return v.f;
}
__device__ __forceinline__ u16 f2bf(float f) {
  union { float f; unsigned int i; } v; v.f = f;
  unsigned int r = v.i + 0x7fffu + ((v.i >> 16) & 1u);
  return (u16)(r >> 16);
}
__device__ __forceinline__ float san(float f) {
  return (fabsf(f) <= 3.0e38f) ? f : 0.f;
}
// dtype-flagged input load: flag 1 = fp32, 0 = bf16
__device__ __forceinline__ float ldin(const void* p, size_t i, int f) {
  return f ? san(((const float*)p)[i]) : bf2f(((const u16*)p)[i]);
}

constexpr int cipow(int b, int e) { return e ? b * cipow(b, e - 1) : 1; }

// async global->LDS, 16B per lane. LDS dest is wave-uniform base + lane*16.
__device__ __forceinline__ void gload16(const u16* g, u16* l) {
  __builtin_amdgcn_global_load_lds(
      (const __attribute__((address_space(1))) void*)g,
      (__attribute__((address_space(3))) void*)l, 16, 0, 0);
}

// ---------------- per-tensor dtype sniffer ----------------
struct PtrArgs { const void* p[22]; int n[22]; };

__global__ void detect_dtypes(PtrArgs a, int* __restrict__ flags) {
  __shared__ int cnt;
  int ti = blockIdx.x;
  if (threadIdx.x == 0) cnt = 0;
  __syncthreads();
  if (ti >= 22) {
    if (threadIdx.x == 0) flags[ti] = 0;
    return;
  }
  const u16* u = (const u16*)a.p[ti];
  int m = a.n[ti]; if (m > 4096) m = 4096;
  int local = 0;
  for (int i = threadIdx.x; i < m; i += blockDim.x) {
    int e = (u[i] >> 7) & 0xFF;
    if (e != 0 && (e < 97 || e > 158)) local++;
  }
  atomicAdd(&cnt, local);
  __syncthreads();
  if (threadIdx.x == 0) flags[ti] = (cnt >= (m >> 6) + 2) ? 1 : 0;
}

// ---------------- weight pre-conversion: flagged (fp32|bf16) -> bf16 arena ----
struct W5 { const void* p[5]; int fi[5]; };

__global__ void conv_w(W5 w, u16* __restrict__ out, const int* __restrict__ flags) {
  int wi = blockIdx.y;
  int f = flags[w.fi[wi]];
  size_t base = (size_t)wi * (CDIM * CDIM);
  int t = blockIdx.x * blockDim.x + threadIdx.x;   // 0 .. CDIM*CDIM/8-1
  size_t e = (size_t)t * 8;
  if (f) {
    const float4* in = (const float4*)w.p[wi];
    float4 a0 = in[t * 2], a1 = in[t * 2 + 1];
    __align__(16) u16 tmp[8];
    tmp[0] = f2bf(san(a0.x)); tmp[1] = f2bf(san(a0.y));
    tmp[2] = f2bf(san(a0.z)); tmp[3] = f2bf(san(a0.w));
    tmp[4] = f2bf(san(a1.x)); tmp[5] = f2bf(san(a1.y));
    tmp[6] = f2bf(san(a1.z)); tmp[7] = f2bf(san(a1.w));
    *(uint4*)&out[base + e] = *(uint4*)tmp;
  } else {
    const uint4* in = (const uint4*)w.p[wi];
    *(uint4*)&out[base + e] = in[t];
  }
}

// ---------------- transpose + zero-pad (dtype-flagged input -> bf16) ----
__global__ void transpose_pad(const void* __restrict__ inv, u16* __restrict__ out,
                              int Lin, int Lout, const int* __restrict__ flags, int fidx) {
  __shared__ u16 t[32][33];
  int f = flags[fidx];
  int b = blockIdx.z;
  int l0 = blockIdx.x * 32, c0 = blockIdx.y * 32;
  int x = threadIdx.x, y = threadIdx.y;
  bool valid = (l0 < Lin);   // Lin % 32 == 0: whole tile valid or whole tile pad
  if (valid) {
    for (int r = 0; r < 4; r++) {
      size_t idx = ((size_t)b * CDIM + c0 + y * 4 + r) * Lin + l0 + x;
      t[y * 4 + r][x] = f2bf(ldin(inv, idx, f));
    }
  }
  __syncthreads();
  for (int r = 0; r < 4; r++) {
    int lr = l0 + y * 4 + r;
    out[((size_t)b * Lout + lr) * CDIM + c0 + x] = valid ? t[x][y * 4 + r] : (u16)0;
  }
}

// ---------------- bf16 MFMA GEMM with BN epilogue (m97 structure) ----------
#define BK 32

__global__ __launch_bounds__(256) void gemm_bn(
    const u16* __restrict__ Wb, const u16* __restrict__ XT, void* __restrict__ Out,
    const void* __restrict__ sc, const void* __restrict__ sh, int Lpad,
    const int* __restrict__ flags, int sci, int shi, int f32out) {
  __shared__ __align__(16) u16 As[128 * BK];
  __shared__ __align__(16) u16 Bs[128 * BK];
  const int K = 1024;
  int tid = threadIdx.x;
  int lane = tid & 63, wave = tid >> 6;
  int m0 = blockIdx.y * 128, n0 = blockIdx.x * 128;
  int wm = (wave >> 1) * 64, wn = (wave & 1) * 64;
  int srow = lane >> 2;
  int scol = (lane & 3) * 8;
  const u16* Ag = Wb + (size_t)(m0 + wave * 32 + srow) * K + scol;
  const u16* Bg = XT + (size_t)(n0 + wave * 32 + srow) * K + scol;
  u16* Asl = &As[(wave * 32 + srow) * BK + scol];
  u16* Bsl = &Bs[(wave * 32 + srow) * BK + scol];
  floatx4 acc[4][4] = {};
  for (int k0 = 0; k0 < K; k0 += BK) {
    __syncthreads();
#pragma unroll
    for (int i = 0; i < 2; i++) {
      gload16(Ag + (size_t)(i * 16) * K + k0, Asl + i * 16 * BK);
      gload16(Bg + (size_t)(i * 16) * K + k0, Bsl + i * 16 * BK);
    }
    __syncthreads();
    int lr = lane & 15, q8 = (lane >> 4) * 8;
    short8 af[4], bfr[4];
#pragma unroll
    for (int f = 0; f < 4; f++) {
      af[f]  = *(const short8*)&As[(wm + f * 16 + lr) * BK + q8];
      bfr[f] = *(const short8*)&Bs[(wn + f * 16 + lr) * BK + q8];
    }
#pragma unroll
    for (int i = 0; i < 4; i++)
#pragma unroll
      for (int j = 0; j < 4; j++)
        acc[i][j] = __builtin_amdgcn_mfma_f32_16x16x32_bf16(af[i], bfr[j], acc[i][j], 0, 0, 0);
  }
  int sf = flags[sci], hf = flags[shi];
  int colL = lane & 15, rq = (lane >> 4) * 4;
  int b = n0 / Lpad;
  int lb = n0 - b * Lpad;
#pragma unroll
  for (int i = 0; i < 4; i++) {
    int gr0 = m0 + wm + i * 16 + rq;
    float s0 = ldin(sc, gr0, sf),     h0 = ldin(sh, gr0, hf);
    float s1 = ldin(sc, gr0 + 1, sf), h1 = ldin(sh, gr0 + 1, hf);
    float s2 = ldin(sc, gr0 + 2, sf), h2 = ldin(sh, gr0 + 2, hf);
    float s3 = ldin(sc, gr0 + 3, sf), h3 = ldin(sh, gr0 + 3, hf);
#pragma unroll
    for (int j = 0; j < 4; j++) {
      int gc = lb + wn + j * 16 + colL;
      size_t base = ((size_t)b * CDIM + gr0) * Lpad + gc;
      float r0 = acc[i][j][0] * s0 + h0;
      float r1 = acc[i][j][1] * s1 + h1;
      float r2 = acc[i][j][2] * s2 + h2;
      float r3 = acc[i][j][3] * s3 + h3;
      if (f32out) {
        float* O = (float*)Out;
        O[base]                    = r0;
        O[base + (size_t)Lpad]     = r1;
        O[base + 2 * (size_t)Lpad] = r2;
        O[base + 3 * (size_t)Lpad] = r3;
      } else {
        u16* O = (u16*)Out;
        O[base]                    = f2bf(r0);
        O[base + (size_t)Lpad]     = f2bf(r1);
        O[base + 2 * (size_t)Lpad] = f2bf(r2);
        O[base + 3 * (size_t)Lpad] = f2bf(r3);
      }
    }
  }
}

// ---------------- attention P precompute ----------------
// P slot stride padded to 16B multiple: base2 -> 4 floats, base3 -> 12 floats.
template<int BASE>
__global__ void p_compute(const u16* __restrict__ qk, float* __restrict__ P,
                          int Lstride, int n, int G) {
  constexpr int PSTR = (BASE == 2) ? 4 : 12;
  int lev = blockIdx.y;
  int t = blockIdx.x * blockDim.x + threadIdx.x;
  if (t >= 32 * G) return;
  int g = t % G, bh = t / G;
  int inner = 1;
  for (int i = 0; i < n - 1 - lev; i++) inner *= BASE;
  int ii = g / inner, kk = g - ii * inner;
  const u16* qp = qk + ((size_t)bh * 128) * Lstride;
  const u16* kp = qk + ((size_t)bh * 128 + 64) * Lstride;
  int lpos[BASE];
#pragma unroll
  for (int j = 0; j < BASE; j++) lpos[j] = (ii * BASE + j) * inner + kk;
  float S[BASE][BASE];
#pragma unroll
  for (int J = 0; J < BASE; J++)
#pragma unroll
    for (int j = 0; j < BASE; j++) S[J][j] = 0.f;
  for (int d = 0; d < 64; d++) {
    float qv[BASE], kv[BASE];
#pragma unroll
    for (int j = 0; j < BASE; j++) {
      qv[j] = bf2f(qp[(size_t)d * Lstride + lpos[j]]);
      kv[j] = bf2f(kp[(size_t)d * Lstride + lpos[j]]);
    }
#pragma unroll
    for (int J = 0; J < BASE; J++)
#pragma unroll
      for (int j = 0; j < BASE; j++) S[J][j] += kv[J] * qv[j];
  }
  float* Pg = P + ((size_t)lev * 32 * G + t) * PSTR;
#pragma unroll
  for (int J = 0; J < BASE; J++) {
    float mx = -1e30f;
#pragma unroll
    for (int j = 0; j < BASE; j++) { S[J][j] *= 0.125f; mx = fmaxf(mx, S[J][j]); }
    float e[BASE]; float sum = 0.f;
#pragma unroll
    for (int j = 0; j < BASE; j++) { e[j] = __expf(S[J][j] - mx); sum += e[j]; }
    float inv = 1.f / sum;
#pragma unroll
    for (int j = 0; j < BASE; j++) Pg[J * BASE + j] = e[j] * inv;
  }
}

// ---------------- plane-layout in-LDS chain machinery ----------------
// LDS: Wl[4][LW] bf16 — plane r holds row row0+r. Staged via global_load_lds
// (wave w stages plane w, 16B/lane, conflict-free). Chain taps are scalar
// b16 LDS ops at 2..4-way (cheap per m136). Groups thread-disjoint.
template<int B, int LW, int inner>
__device__ __forceinline__ void group_pl(u16* __restrict__ Wl,
                                         const float4* __restrict__ Pg, int g) {
  int ii = g / inner, kk = g - ii * inner;
  int base = ii * (B * inner) + kk;
  if constexpr (B == 2) {
    float4 pv = Pg[0];
#pragma unroll
    for (int r = 0; r < 4; r++) {
      u16* w = Wl + r * LW;
      float i0 = bf2f(w[base]), i1 = bf2f(w[base + inner]);
      w[base]         = f2bf(pv.x * i0 + pv.y * i1);
      w[base + inner] = f2bf(pv.z * i0 + pv.w * i1);
    }
  } else {
    float4 A = Pg[0], Bv = Pg[1], Cv = Pg[2];
#pragma unroll
    for (int r = 0; r < 4; r++) {
      u16* w = Wl + r * LW;
      float i0 = bf2f(w[base]), i1 = bf2f(w[base + inner]), i2 = bf2f(w[base + 2 * inner]);
      w[base]             = f2bf(A.x  * i0 + A.y  * i1 + A.z  * i2);
      w[base + inner]     = f2bf(A.w  * i0 + Bv.x * i1 + Bv.y * i2);
      w[base + 2 * inner] = f2bf(Bv.z * i0 + Bv.w * i1 + Cv.x * i2);
    }
  }
}

template<int B, int N, int LW, int p, bool up>
__device__ __forceinline__ void chainrec_pl(u16* __restrict__ Wl,
                                            const float* __restrict__ Pb, int bh) {
  constexpr int G = cipow(B, N) / B;
  constexpr int PSTR = (B == 2) ? 4 : 12;
  constexpr size_t PLEV = (size_t)32 * G * PSTR;
  constexpr int inner = cipow(B, p);
  __syncthreads();   // first instance also drains the global_load_lds staging
  const float* Pl = Pb + (size_t)(N - 1 - p) * PLEV + (size_t)bh * G * PSTR;
#pragma unroll 2
  for (int it = 0; it < G / 256; it++) {
    int g = it * 256 + (int)threadIdx.x;
    group_pl<B, LW, inner>(Wl, (const float4*)(Pl + (size_t)g * PSTR), g);
  }
  if constexpr ((G % 256) != 0) {
    int g = (G / 256) * 256 + (int)threadIdx.x;
    if (g < G) group_pl<B, LW, inner>(Wl, (const float4*)(Pl + (size_t)g * PSTR), g);
  }
  if constexpr (up) {
    if constexpr (p + 1 < N) chainrec_pl<B, N, LW, p + 1, true>(Wl, Pb, bh);
  } else {
    if constexpr (p > 0) chainrec_pl<B, N, LW, p - 1, false>(Wl, Pb, bh);
  }
}

// stage v0 rows into planes: wave w -> plane w, LW multiple of 512 shorts.
template<int LW, int LSTR>
__device__ __forceinline__ void loadV_pl(u16* __restrict__ Wl,
                                         const u16* __restrict__ v0, int row0) {
  int wave = (int)threadIdx.x >> 6, lane = (int)threadIdx.x & 63;
  const u16* vr = v0 + (size_t)(row0 + wave) * LSTR;
  u16* wp = Wl + wave * LW;
#pragma unroll
  for (int it = 0; it < LW / 512; it++)
    gload16(vr + it * 512 + lane * 8, wp + it * 512 + lane * 8);
}

// XCD swizzle: 1024 blocks % 8 == 0 -> bijective; the 32 blocks of one bh
// land on one XCD so the shared P set stays L2-resident.
__device__ __forceinline__ int xcd_blk() {
  int cpx = (int)gridDim.x >> 3;
  return ((int)blockIdx.x & 7) * cpx + ((int)blockIdx.x >> 3);
}

// ---------------- chain 1: ascending digits, stash v1 ----------------
template<int BASE, int N, int LSTR, int LW>
__global__ __launch_bounds__(256, 4) void chain1_k(
    const u16* __restrict__ v0, u16* __restrict__ v1s,
    const float* __restrict__ Pb) {
  __shared__ __align__(16) u16 Wl[4 * LW];
  int row0 = xcd_blk() * 4, bh = row0 >> 7;
  loadV_pl<LW, LSTR>(Wl, v0, row0);
  chainrec_pl<BASE, N, LW, 0, true>(Wl, Pb, bh);
  __syncthreads();
  int l0 = (int)threadIdx.x * 16;       // only first 4096 positions needed
#pragma unroll
  for (int r = 0; r < 4; r++) {
    short8 a = *(const short8*)&Wl[r * LW + l0];
    short8 b = *(const short8*)&Wl[r * LW + l0 + 8];
    size_t vb = (size_t)(row0 + r) * 4096 + l0;
    *(short8*)&v1s[vb] = a;
    *(short8*)&v1s[vb + 8] = b;
  }
}

// ---------------- chain 2: descending digits + fused epilogue ----------
// y = x + v1s + Wl(v2) + BN(dwconv3(v0 re-read from global, L3-hot)).
// xres may alias y (stage 3): thread reads its elems before writing them.
template<int BASE, int N, int LSTR, int LW>
__global__ __launch_bounds__(256, 4) void chain2_k(
    const u16* __restrict__ v0, const void* __restrict__ xres,
    const void* __restrict__ wpe, const void* __restrict__ spe,
    const void* __restrict__ bpe, u16* __restrict__ y,
    const u16* __restrict__ v1s, const float* __restrict__ Pb,
    const int* __restrict__ flags, int xfi, int wpi, int spi, int bpi) {
  constexpr int L = cipow(BASE, N);
  __shared__ __align__(16) u16 Wl[4 * LW];
  int row0 = xcd_blk() * 4, bh = row0 >> 7;
  loadV_pl<LW, LSTR>(Wl, v0, row0);
  chainrec_pl<BASE, N, LW, N - 1, false>(Wl, Pb, bh);
  __syncthreads();

  int l0 = (int)threadIdx.x * 16;
  int c0 = row0 & (CDIM - 1);
  int xf = flags[xfi], wf = flags[wpi], sf = flags[spi], bfg = flags[bpi];
#pragma unroll
  for (int r = 0; r < 4; r++) {
    int cr = c0 + r;
    const u16* vr = v0 + (size_t)(row0 + r) * LSTR;
    float w0 = ldin(wpe, (size_t)cr * 3, wf);
    float w1 = ldin(wpe, (size_t)cr * 3 + 1, wf);
    float w2 = ldin(wpe, (size_t)cr * 3 + 2, wf);
    float scv = ldin(spe, cr, sf), bcv = ldin(bpe, cr, bfg);
    // v0 window (global, L2/L3-hot after loadV)
    short8 vc0 = *(const short8*)&vr[l0];
    short8 vc1 = *(const short8*)&vr[l0 + 8];
    float vcf[16];
#pragma unroll
    for (int k = 0; k < 8; k++) {
      vcf[k] = bf2f((u16)vc0[k]);
      vcf[k + 8] = bf2f((u16)vc1[k]);
    }
    float vml = (l0 > 0) ? bf2f(vr[l0 - 1]) : 0.f;
    float vpr = (l0 + 16 < L) ? bf2f(vr[l0 + 16]) : 0.f;
    size_t xb = (size_t)(row0 + r) * 4096 + l0;
    float xr[16];
    if (xf) {
      const float* X = (const float*)xres;
#pragma unroll
      for (int k = 0; k < 16; k += 4) {
        float4 x4 = *(const float4*)&X[xb + k];
        xr[k] = san(x4.x); xr[k + 1] = san(x4.y);
        xr[k + 2] = san(x4.z); xr[k + 3] = san(x4.w);
      }
    } else {
      const u16* X = (const u16*)xres;
#pragma unroll
      for (int k8 = 0; k8 < 2; k8++) {
        short8 x8 = *(const short8*)&X[xb + k8 * 8];
#pragma unroll
        for (int k = 0; k < 8; k++) xr[k8 * 8 + k] = bf2f((u16)x8[k]);
      }
    }
    short8 s10 = *(const short8*)&v1s[xb];
    short8 s11 = *(const short8*)&v1s[xb + 8];
    short8 t0 = *(const short8*)&Wl[r * LW + l0];
    short8 t1 = *(const short8*)&Wl[r * LW + l0 + 8];
    short8 o0, o1;
#pragma unroll
    for (int k = 0; k < 16; k++) {
      float vm = k ? vcf[k - 1] : vml;
      float vp = (k < 15) ? vcf[k + 1] : vpr;
      float pe = (w0 * vm + w1 * vcf[k] + w2 * vp) * scv + bcv;
      float v1v = bf2f((u16)((k < 8) ? s10[k] : s11[k - 8]));
      float v2v = bf2f((u16)((k < 8) ? t0[k] : t1[k - 8]));
      float res = xr[k] + v1v + v2v + pe;
      if (k < 8) o0[k] = (short)f2bf(res); else o1[k - 8] = (short)f2bf(res);
    }
    *(short8*)&y[xb] = o0;
    *(short8*)&y[xb + 8] = o1;
  }
}

extern "C" void kernel_launch(void* const* d_in, const int* in_sizes, int n_in,
                              void* d_out, int out_size, void* d_ws, size_t ws_size,
                              hipStream_t stream) {
  const int W = 4096;
  const int Ls2 = 4096;                 // stage2 stride == L2
  const int Ls3 = 6656;                 // stage3: stride (52*128), L3 = 6561
  const int G2 = 2048, G3 = 2187;       // groups per (b,H)
  const size_t S3e = (size_t)NB * CDIM * Ls3;   // 27,262,976 elements

  // Arena: 3 bf16 slots + flags + bf16 weight arena ≈ 174 MB.
  // Pbuf aliases slotA (xT dead after the two GEMMs, P dead before the next
  // transpose rewrites slotA). slotB doubles as the chain-1 stash (qk dead
  // after p_compute).
  char* p = (char*)d_ws;
  auto alloc = [&](size_t bytes) { char* r = p; p += (bytes + 255) & ~(size_t)255; return r; };
  u16* slotA = (u16*)alloc(S3e * 2);   // xT ; later aliased by Pbuf
  u16* slotB = (u16*)alloc(S3e * 2);   // qk ; later chain-1 stash
  u16* slotC = (u16*)alloc(S3e * 2);   // v0
  int* flags = (int*)alloc(64 * 4);
  u16* warena = (u16*)alloc((size_t)5 * CDIM * CDIM * 2);  // 5 bf16 weight copies
  float* Pbuf = (float*)slotA;         // max P: base3 = 8*32*2187*12*4 B = 33.6 MB
  (void)ws_size; (void)n_in; (void)out_size;

  // y2/y3 staging (bf16) lives in the front half of d_out.
  u16* ybuf = (u16*)d_out;

  // ---- dtype sniff (writes flags[0..21]; flags[22]=0 = bf16 sentinel) ----
  PtrArgs pa;
  for (int i = 0; i < 22; i++) { pa.p[i] = d_in[i]; pa.n[i] = in_sizes[i]; }
  detect_dtypes<<<23, 256, 0, stream>>>(pa, flags);
  const int BF = 22;  // sentinel flag index (bf16)

  // ---- pre-convert the 5 GEMM weights to bf16 arena (flag-driven) ----
  W5 w5;
  const int widx[5] = {1, 4, 10, 13, 19};
  for (int i = 0; i < 5; i++) { w5.p[i] = d_in[widx[i]]; w5.fi[i] = widx[i]; }
  conv_w<<<dim3(CDIM * CDIM / 8 / 256, 5), 256, 0, stream>>>(w5, warena, flags);
  u16* wb_qk2 = warena;
  u16* wb_v2  = warena + (size_t)1 * CDIM * CDIM;
  u16* wb_qk3 = warena + (size_t)2 * CDIM * CDIM;
  u16* wb_v3  = warena + (size_t)3 * CDIM * CDIM;
  u16* wb_pr  = warena + (size_t)4 * CDIM * CDIM;

  dim3 tb(32, 8);
  const int cblocks = NB * CDIM / 4;    // 1024

  // ================= stage base=2 (n=12, L=4096, no pad) =================
  transpose_pad<<<dim3(Ls2 / 32, CDIM / 32, NB), tb, 0, stream>>>(d_in[0], slotA, W, Ls2, flags, 0);
  gemm_bn<<<dim3(NB * Ls2 / 128, CDIM / 128), 256, 0, stream>>>(
      wb_qk2, slotA, slotB, d_in[2], d_in[3], Ls2, flags, 2, 3, 0);
  gemm_bn<<<dim3(NB * Ls2 / 128, CDIM / 128), 256, 0, stream>>>(
      wb_v2, slotA, slotC, d_in[5], d_in[6], Ls2, flags, 5, 6, 0);
  p_compute<2><<<dim3((32 * G2 + 255) / 256, 12), 256, 0, stream>>>(slotB, Pbuf, Ls2, 12, G2);
  chain1_k<2, 12, 4096, 4096><<<cblocks, 256, 0, stream>>>(slotC, slotB, Pbuf);
  chain2_k<2, 12, 4096, 4096><<<cblocks, 256, 0, stream>>>(
      slotC, d_in[0], d_in[7], d_in[8], d_in[9], ybuf, slotB, Pbuf, flags, 0, 7, 8, 9);

  // ================= stage base=3 (n=8, L=6561, stride 6656) =================
  transpose_pad<<<dim3(Ls3 / 32, CDIM / 32, NB), tb, 0, stream>>>(ybuf, slotA, W, Ls3, flags, BF);
  gemm_bn<<<dim3(NB * Ls3 / 128, CDIM / 128), 256, 0, stream>>>(
      wb_qk3, slotA, slotB, d_in[11], d_in[12], Ls3, flags, 11, 12, 0);
  gemm_bn<<<dim3(NB * Ls3 / 128, CDIM / 128), 256, 0, stream>>>(
      wb_v3, slotA, slotC, d_in[14], d_in[15], Ls3, flags, 14, 15, 0);
  p_compute<3><<<dim3((32 * G3 + 255) / 256, 8), 256, 0, stream>>>(slotB, Pbuf, Ls3, 8, G3);
  chain1_k<3, 8, 6656, 6656><<<cblocks, 256, 0, stream>>>(slotC, slotB, Pbuf);
  chain2_k<3, 8, 6656, 6656><<<cblocks, 256, 0, stream>>>(
      slotC, ybuf, d_in[16], d_in[17], d_in[18], ybuf, slotB, Pbuf, flags, BF, 16, 17, 18);

  // ================= final projection (fp32 output!) =================
  transpose_pad<<<dim3(Ls2 / 32, CDIM / 32, NB), tb, 0, stream>>>(ybuf, slotA, W, Ls2, flags, BF);
  gemm_bn<<<dim3(NB * Ls2 / 128, CDIM / 128), 256, 0, stream>>>(
      wb_pr, slotA, d_out, d_in[20], d_in[21], Ls2, flags, 20, 21, 1);
}